// Round 6
// baseline (1048.711 us; speedup 1.0000x reference)
//
#include <hip/hip_runtime.h>

// AGLI_5703716569604 — round 5: MFMA bf16 softmax-apply GEMMs + attT + streaming att2.
// B=2, ch1=64, ch2=128, H=W=64, N=4096, att [B,4096,4096].

#define LB __launch_bounds__(256)

constexpr float BN_SCALE = 0.99999500003749968f; // 1/sqrt(1+1e-5)
constexpr float NEG_BIG  = -3.402823466e38f;

typedef __attribute__((ext_vector_type(8))) short short8v;
typedef __attribute__((ext_vector_type(4))) float f32x4;

__device__ __forceinline__ ushort bf16rne(float f) {
    unsigned u = __float_as_uint(f);
    unsigned r = (u + 0x7FFFu + ((u >> 16) & 1u)) >> 16;
    return (ushort)r;
}

// ---------------------------------------------------------------------------
// Stage one 34x34 halo tile (stride 35) for input channel image ib.
__device__ __forceinline__ void stage_tile(const float* __restrict__ ib,
                                           float* __restrict__ buf,
                                           int x0, int y0, int tid)
{
    #pragma unroll
    for (int r = 0; r < 5; ++r) {
        const int e = tid + r * 256;
        if (e < 1156) {
            const int hy = e / 34, hx = e % 34;
            const int yy = y0 + hy - 1, xx = x0 + hx - 1;
            float v = 0.f;
            if ((unsigned)yy < 64u && (unsigned)xx < 64u)
                v = ib[yy * 64 + xx];
            buf[hy * 35 + hx] = v;
        }
    }
}

// ---------------------------------------------------------------------------
// 3x3 conv partial over an ic-chunk (unchanged from round 4).
__global__ LB void conv3x3_big(
    const float* __restrict__ in, const float* __restrict__ gconst,
    const float* __restrict__ w, const float* __restrict__ bias,
    float* __restrict__ part, int Cg, int Cin, int Cout, int ICS)
{
    __shared__ float buf[2][34 * 35];
    __shared__ float wg[8][10];
    const int tid = threadIdx.x;
    const int tx = tid & 15, ty = tid >> 4;
    const int x0 = (blockIdx.x & 1) * 32, y0 = (blockIdx.x >> 1) * 32;
    const int oc0 = blockIdx.y * 8;
    const int b = blockIdx.z / ICS, s = blockIdx.z % ICS;
    const int chunk = Cin / ICS;
    const int ic0 = s * chunk;
    const int Ct = Cg + Cin;
    const int HW = 4096;

    float acc[8][4];
    #pragma unroll
    for (int oc = 0; oc < 8; ++oc)
        #pragma unroll
        for (int p = 0; p < 4; ++p) acc[oc][p] = 0.f;

    if (s == 0) {
        if (bias) {
            #pragma unroll
            for (int oc = 0; oc < 8; ++oc) {
                const float bv = bias[oc0 + oc];
                #pragma unroll
                for (int p = 0; p < 4; ++p) acc[oc][p] = bv;
            }
        }
        if (Cg > 0) {
            for (int e = tid; e < 72; e += 256) {
                const int oc = e / 9, k = e % 9;
                float sm = 0.f;
                for (int ic = 0; ic < Cg; ++ic)
                    sm += gconst[b * Cg + ic] * w[((long)(oc0 + oc) * Ct + ic) * 9 + k];
                wg[oc][k] = sm;
            }
            __syncthreads();
            #pragma unroll
            for (int k = 0; k < 9; ++k) {
                const int dy = k / 3 - 1, dx = k % 3 - 1;
                #pragma unroll
                for (int pr = 0; pr < 2; ++pr)
                    #pragma unroll
                    for (int pc = 0; pc < 2; ++pc) {
                        const int yy = y0 + ty * 2 + pr + dy;
                        const int xx = x0 + tx * 2 + pc + dx;
                        if ((unsigned)yy < 64u && (unsigned)xx < 64u) {
                            #pragma unroll
                            for (int oc = 0; oc < 8; ++oc)
                                acc[oc][pr * 2 + pc] += wg[oc][k];
                        }
                    }
            }
        }
    }

    const float* ib = in + ((long)b * Cin + ic0) * HW;
    stage_tile(ib, buf[0], x0, y0, tid);
    __syncthreads();
    int cur = 0;
    for (int i = 0; i < chunk; ++i) {
        if (i + 1 < chunk)
            stage_tile(ib + (long)(i + 1) * HW, buf[cur ^ 1], x0, y0, tid);
        float win[4][4];
        const float* bp = buf[cur] + (ty * 2) * 35 + tx * 2;
        #pragma unroll
        for (int r = 0; r < 4; ++r) {
            const float2 a = *(const float2*)&bp[r * 35];
            const float2 c = *(const float2*)&bp[r * 35 + 2];
            win[r][0] = a.x; win[r][1] = a.y; win[r][2] = c.x; win[r][3] = c.y;
        }
        const float* wq = w + ((long)oc0 * Ct + Cg + ic0 + i) * 9;
        #pragma unroll
        for (int oc = 0; oc < 8; ++oc) {
            const float* wo = wq + (long)oc * Ct * 9;
            #pragma unroll
            for (int dy = 0; dy < 3; ++dy)
                #pragma unroll
                for (int dx = 0; dx < 3; ++dx) {
                    const float wv = wo[dy * 3 + dx];
                    #pragma unroll
                    for (int pr = 0; pr < 2; ++pr)
                        #pragma unroll
                        for (int pc = 0; pc < 2; ++pc)
                            acc[oc][pr * 2 + pc] =
                                fmaf(wv, win[pr + dy][pc + dx], acc[oc][pr * 2 + pc]);
                }
        }
        __syncthreads();
        cur ^= 1;
    }

    #pragma unroll
    for (int oc = 0; oc < 8; ++oc) {
        #pragma unroll
        for (int pr = 0; pr < 2; ++pr) {
            float* q = part + (((long)s * 2 + b) * Cout + oc0 + oc) * (long)HW
                       + (y0 + ty * 2 + pr) * 64 + x0 + tx * 2;
            *(float2*)q = make_float2(acc[oc][pr * 2], acc[oc][pr * 2 + 1]);
        }
    }
}

// ---------------------------------------------------------------------------
__global__ LB void conv_combine(const float* __restrict__ part,
                                const float* __restrict__ bn,
                                const float* __restrict__ residual,
                                float* __restrict__ out,
                                int Cout, int ICS)
{
    const long idx = (long)blockIdx.x * 256 + threadIdx.x;
    const int hw = (int)(idx & 4095);
    const long t = idx >> 12;
    const int c = (int)(t % Cout);
    const int b = (int)(t / Cout);
    float v = 0.f;
    for (int s = 0; s < ICS; ++s)
        v += part[(((long)s * 2 + b) * Cout + c) * 4096 + hw];
    const float scale = bn[c] * BN_SCALE, beta = bn[Cout + c];
    float r = fmaxf(fmaf(v, scale, beta), 0.f);
    if (residual) r += residual[idx];
    out[idx] = r;
}

// ---------------------------------------------------------------------------
__global__ LB void gap_kernel(const float* __restrict__ in,
                              float* __restrict__ o1, float* __restrict__ o2,
                              int C, int HW)
{
    const int c = blockIdx.x, b = blockIdx.y;
    const float* p = in + ((long)b * C + c) * HW;
    float s = 0.f;
    for (int i = threadIdx.x; i < HW; i += 256) s += p[i];
    #pragma unroll
    for (int off = 32; off; off >>= 1) s += __shfl_down(s, off);
    __shared__ float red[4];
    if ((threadIdx.x & 63) == 0) red[threadIdx.x >> 6] = s;
    __syncthreads();
    if (threadIdx.x == 0) {
        const float t = (red[0] + red[1] + red[2] + red[3]) / (float)HW;
        o1[b * C + c] = t;
        o2[b * C + c] = t;
    }
}

// ---------------------------------------------------------------------------
// att[b,n,m] = sum_c fs[b,c,n] * fc[b,c,m], C=32. Also writes attT[b,m,n].
__global__ LB void att_gemm(const float* __restrict__ fs, const float* __restrict__ fc,
                            float* __restrict__ att, float* __restrict__ attT, int N)
{
    __shared__ float lfs[32][17];
    const int tid = threadIdx.x;
    const int m  = blockIdx.x * 256 + tid;
    const int n0 = blockIdx.y * 16;
    const int b  = blockIdx.z;
    for (int i = tid; i < 32 * 16; i += 256) {
        const int c = i >> 4, nn = i & 15;
        lfs[c][nn] = fs[((long)b * 32 + c) * N + n0 + nn];
    }
    __syncthreads();
    float acc[16];
    #pragma unroll
    for (int i = 0; i < 16; ++i) acc[i] = 0.f;
    const float* fcp = fc + (long)b * 32 * N + m;
    #pragma unroll
    for (int c = 0; c < 32; ++c) {
        const float f = fcp[(long)c * N];
        #pragma unroll
        for (int nn = 0; nn < 16; ++nn) acc[nn] = fmaf(lfs[c][nn], f, acc[nn]);
    }
    float* op = att + ((long)b * N + n0) * N + m;
    #pragma unroll
    for (int nn = 0; nn < 16; ++nn) op[(long)nn * N] = acc[nn];
    // transposed copy: row m, cols n0..n0+15 (one full 64B line per lane)
    float* opT = attT + ((long)b * N + m) * N + n0;
    #pragma unroll
    for (int q = 0; q < 4; ++q)
        *(float4*)&opT[q * 4] = make_float4(acc[q*4], acc[q*4+1], acc[q*4+2], acc[q*4+3]);
}

// ---------------------------------------------------------------------------
// Column-wise online (max, sum-exp) over an n-chunk. grid: (N/256, S, B)
__global__ LB void colstats_part(const float* __restrict__ att,
                                 float* __restrict__ Mp, float* __restrict__ Sp,
                                 int N, int S)
{
    const int m = blockIdx.x * 256 + threadIdx.x;
    const int s = blockIdx.y, b = blockIdx.z;
    const int chunk = N / S;
    const float* p = att + (long)b * N * N + (long)s * chunk * N + m;
    float mx = NEG_BIG, sum = 0.f;
    for (int n = 0; n < chunk; ++n) {
        const float v = p[(long)n * N];
        if (v > mx) { sum = sum * __expf(mx - v) + 1.f; mx = v; }
        else        { sum += __expf(v - mx); }
    }
    Mp[((long)b * S + s) * N + m] = mx;
    Sp[((long)b * S + s) * N + m] = sum;
}

// grid: (N/256, B); combines S partial (max,sumexp) sets.
__global__ LB void colstats_comb(const float* __restrict__ Mp, const float* __restrict__ Sp,
                                 float* __restrict__ M, float* __restrict__ Sm,
                                 int N, int S)
{
    const int m = blockIdx.x * 256 + threadIdx.x;
    const int b = blockIdx.y;
    float mx = NEG_BIG, sum = 0.f;
    for (int s = 0; s < S; ++s) {
        const float m2 = Mp[((long)b * S + s) * N + m];
        const float s2 = Sp[((long)b * S + s) * N + m];
        const float mn = fmaxf(mx, m2);
        sum = sum * __expf(mx - mn) + s2 * __expf(m2 - mn);
        mx = mn;
    }
    M[(long)b * N + m]  = mx;
    Sm[(long)b * N + m] = sum;
}

// ---------------------------------------------------------------------------
// Row-wise (max, sum-exp). grid: (N, B), block 256
__global__ LB void rowstats(const float* __restrict__ att,
                            float* __restrict__ Mr, float* __restrict__ Sr, int N)
{
    const int n = blockIdx.x, b = blockIdx.y;
    const float* p = att + ((long)b * N + n) * N;
    float mx = NEG_BIG, sum = 0.f;
    for (int m = threadIdx.x; m < N; m += 256) {
        const float v = p[m];
        if (v > mx) { sum = sum * __expf(mx - v) + 1.f; mx = v; }
        else        { sum += __expf(v - mx); }
    }
    #pragma unroll
    for (int off = 32; off; off >>= 1) {
        const float m2 = __shfl_down(mx, off);
        const float s2 = __shfl_down(sum, off);
        const float mn = fmaxf(mx, m2);
        sum = sum * __expf(mx - mn) + s2 * __expf(m2 - mn);
        mx = mn;
    }
    __shared__ float rm[4], rs[4];
    const int lane = threadIdx.x & 63, wv = threadIdx.x >> 6;
    if (lane == 0) { rm[wv] = mx; rs[wv] = sum; }
    __syncthreads();
    if (threadIdx.x == 0) {
        mx = rm[0]; sum = rs[0];
        for (int w = 1; w < 4; ++w) {
            const float mn = fmaxf(mx, rm[w]);
            sum = sum * __expf(mx - mn) + rs[w] * __expf(rm[w] - mn);
            mx = mn;
        }
        Mr[(long)b * N + n] = mx;
        Sr[(long)b * N + n] = sum;
    }
}

// ---------------------------------------------------------------------------
// f32 -> bf16 conversion (vectorized). n multiple of 1024.
__global__ LB void to_bf16(const float* __restrict__ in, ushort* __restrict__ out, long n)
{
    const long i = ((long)blockIdx.x * 256 + threadIdx.x) * 4;
    if (i >= n) return;
    const float4 v = *(const float4*)&in[i];
    ushort4 o;
    o.x = bf16rne(v.x); o.y = bf16rne(v.y); o.z = bf16rne(v.z); o.w = bf16rne(v.w);
    *(ushort4*)&out[i] = o;
}

// ---------------------------------------------------------------------------
// MFMA softmax-apply GEMM (both outs & outc use this form):
//   part_s[b,row,col] = sum_{k in chunk s} X[b,row,k] * exp(A[b,col,k] - Mv[b,col])
// A = att (outc) or attT (outs). X is bf16 [B][MROWS][N].
// grid: (N/32 col-tiles, 2 K-splits, B), block 256 = 4 waves.
// Block tile: MROWS x 32 cols; wave (w&1)=col-16-tile, (w>>1)=row half.
template<int MROWS>
__global__ LB void sm_gemm_mfma(const ushort* __restrict__ Xbf,
                                const float* __restrict__ A,
                                const float* __restrict__ Mv,
                                float* __restrict__ p0, float* __restrict__ p1,
                                int N)
{
    constexpr int RT = MROWS / 32;          // row-tiles per wave (128->4, 64->2)
    __shared__ ushort ldsB[32][40];         // [col][k] bf16, 80B row stride

    const int tid = threadIdx.x;
    const int wave = tid >> 6, lane = tid & 63;
    const int col0 = blockIdx.x * 32;
    const int s = blockIdx.y, b = blockIdx.z;
    const int K0 = s * (N / 2);

    const int scol = tid >> 3, sq = tid & 7;    // staging: col 0..31, 4-k granule
    const int wct = wave & 1;                   // col-16-tile
    const int wrh = wave >> 1;                  // row half
    const int fr = lane & 15, fg = lane >> 4;   // fragment row/col, k-group

    f32x4 acc[RT];
    #pragma unroll
    for (int i = 0; i < RT; ++i) acc[i] = (f32x4){0.f, 0.f, 0.f, 0.f};

    const float* ab = A + ((long)b * N + col0) * N;
    const ushort* xb = Xbf + (long)b * MROWS * N;
    const float mv = Mv[(long)b * N + col0 + scol];

    for (int k0 = K0; k0 < K0 + N / 2; k0 += 32) {
        __syncthreads();
        // stage E[col][k] = bf16(exp(A[col0+col][k] - Mv[col]))
        const float4 v = *(const float4*)&ab[(long)scol * N + k0 + sq * 4];
        ushort4 bfv;
        bfv.x = bf16rne(__expf(v.x - mv));
        bfv.y = bf16rne(__expf(v.y - mv));
        bfv.z = bf16rne(__expf(v.z - mv));
        bfv.w = bf16rne(__expf(v.w - mv));
        *(ushort4*)&ldsB[scol][sq * 4] = bfv;
        __syncthreads();
        // B fragment: lane -> B[k=8*fg+j][col=wct*16+fr], contiguous in ldsB row
        const short8v bfrag = *(const short8v*)&ldsB[wct * 16 + fr][8 * fg];
        #pragma unroll
        for (int rt = 0; rt < RT; ++rt) {
            const int row = wrh * (MROWS / 2) + rt * 16 + fr;
            const short8v afrag = *(const short8v*)&xb[(long)row * N + k0 + 8 * fg];
            acc[rt] = __builtin_amdgcn_mfma_f32_16x16x32_bf16(afrag, bfrag, acc[rt], 0, 0, 0);
        }
    }

    float* pp = (s == 0) ? p0 : p1;
    #pragma unroll
    for (int rt = 0; rt < RT; ++rt) {
        #pragma unroll
        for (int r = 0; r < 4; ++r) {
            const int row = wrh * (MROWS / 2) + rt * 16 + (lane >> 4) * 4 + r;
            const int col = col0 + wct * 16 + (lane & 15);
            pp[((long)b * MROWS + row) * N + col] = acc[rt][r];
        }
    }
}

// Sum 2 K-split partials and divide by per-column softmax denom.
template<int C>
__global__ LB void sm_reduce2(const float* __restrict__ p0, const float* __restrict__ p1,
                              const float* __restrict__ denom, float* __restrict__ outp, int N)
{
    const long idx = (long)blockIdx.x * 256 + threadIdx.x;
    const int m = (int)(idx & (long)(N - 1));
    const int b = (int)(idx / ((long)C * N));
    outp[idx] = (p0[idx] + p1[idx]) / denom[(long)b * N + m];
}

// ---------------------------------------------------------------------------
// Streaming att2 = att + attT (in place) with fused per-chunk column stats.
// grid: (16 col-stripes, 32 row-chunks, B). Mp2/Sp2: [B,32,N] comb layout.
__global__ LB void att2_stream(float* __restrict__ att, const float* __restrict__ attT,
                               float* __restrict__ Mp2, float* __restrict__ Sp2, int N)
{
    const int col = blockIdx.x * 256 + threadIdx.x;
    const int y = blockIdx.y, b = blockIdx.z;
    const long base = (long)b * N * N + (long)y * 128 * N + col;
    float mx = NEG_BIG, sum = 0.f;
    for (int r = 0; r < 128; ++r) {
        const float v = att[base + (long)r * N] + attT[base + (long)r * N];
        att[base + (long)r * N] = v;
        if (v > mx) { sum = sum * __expf(mx - v) + 1.f; mx = v; }
        else        { sum += __expf(v - mx); }
    }
    Mp2[((long)b * 32 + y) * N + col] = mx;
    Sp2[((long)b * 32 + y) * N + col] = sum;
}

// ---------------------------------------------------------------------------
// Fused: att3 = 2*exp(att2 - M2[m])/S2[m], then 3x3 conv + BN + ReLU.
__global__ LB void attmap_conv(const float* __restrict__ att2,
                               const float* __restrict__ M2, const float* __restrict__ S2,
                               const float* __restrict__ w, const float* __restrict__ g,
                               float* __restrict__ out, int N)
{
    __shared__ float t[6][67];
    const int tid = threadIdx.x;
    const int tx = tid & 63, ty = tid >> 6;
    const int x0 = (blockIdx.x & 63) * 64;
    const int y0 = (blockIdx.x >> 6) * 4;
    const int b = blockIdx.y;
    const float* ap = att2 + (long)b * N * N;
    const float* m2p = M2 + (long)b * N;
    const float* s2p = S2 + (long)b * N;
    for (int e = tid; e < 396; e += 256) {
        const int hy = e / 66, hx = e % 66;
        const int yy = y0 + hy - 1, xx = x0 + hx - 1;
        float v = 0.f;
        if ((unsigned)yy < (unsigned)N && (unsigned)xx < (unsigned)N)
            v = 2.f * __expf(ap[(long)yy * N + xx] - m2p[xx]) *
                __builtin_amdgcn_rcpf(s2p[xx]);
        t[hy][hx] = v;
    }
    __syncthreads();
    float acc = 0.f;
    #pragma unroll
    for (int k = 0; k < 9; ++k)
        acc = fmaf(w[k], t[ty + k / 3][tx + k % 3], acc);
    const float scale = g[0] * BN_SCALE, beta = g[1];
    out[(long)b * N * N + (long)(y0 + ty) * N + x0 + tx] =
        fmaxf(fmaf(acc, scale, beta), 0.f);
}

// ===========================================================================
extern "C" void kernel_launch(void* const* d_in, const int* in_sizes, int n_in,
                              void* d_out, int out_size, void* d_ws, size_t ws_size,
                              hipStream_t stream)
{
    const float* xs   = (const float*)d_in[0];
    const float* xc   = (const float*)d_in[1];
    const float* w_g1 = (const float*)d_in[2];
    const float* g_g1 = (const float*)d_in[3];
    const float* w_g2 = (const float*)d_in[4];
    const float* g_g2 = (const float*)d_in[5];
    const float* w_ls = (const float*)d_in[6];
    const float* b_ls = (const float*)d_in[7];
    const float* g_ls = (const float*)d_in[8];
    const float* w_lc = (const float*)d_in[9];
    const float* b_lc = (const float*)d_in[10];
    const float* g_lc = (const float*)d_in[11];
    const float* w_c1 = (const float*)d_in[12];
    const float* g_c1 = (const float*)d_in[13];
    const float* w_c2 = (const float*)d_in[14];
    const float* g_c2 = (const float*)d_in[15];
    const float* w_o1 = (const float*)d_in[16];
    const float* g_o1 = (const float*)d_in[17];
    const float* w_o2 = (const float*)d_in[18];
    const float* g_o2 = (const float*)d_in[19];
    const float* w_oa = (const float*)d_in[20];
    const float* g_oa = (const float*)d_in[21];

    const int B = 2, HW = 4096, N = 4096;

    // ---- workspace layout (float offsets) ----
    float* ws = (float*)d_ws;
    float* xs1    = ws;                       // 524288
    float* xc1    = ws + 524288;              // 1048576
    float* fs     = ws + 1572864;             // 262144
    float* fc     = ws + 1835008;             // 262144
    float* t32    = ws + 2097152;             // 262144
    float* outs_w = ws + 2359296;             // 524288
    float* outc_w = ws + 2883584;             // 1048576
    float* gs_w   = ws + 3932160;             // 64
    float* gc_w   = ws + 3932224;             // 64
    float* Mc     = ws + 3932288;             // 8192
    float* Sc     = ws + 3940480;             // 8192
    float* Mr     = ws + 3948672;             // 8192
    float* Sr     = ws + 3956864;             // 8192
    float* M2     = ws + 3965056;             // 8192
    float* S2     = ws + 3973248;             // 8192
    float* Mp     = ws + 3981440;             // 131072
    float* Sp     = ws + 4112512;             // 131072
    float* att    = ws + 4243584;             // 33554432
    float* cpart  = att;                      // conv partials alias (att dead then)
    // GEMM K-split partials (s=1) + bf16 xs1 — dead-slot reuse:
    float* pg1    = ws + 1572864;             // up to 1,310,720 floats (fs..outs_w gap)
    ushort* xs1bf = (ushort*)(ws + 2097152);  // 524,288 ushorts (t32 slot)

    // ---- d_out layout ----
    float* out = (float*)d_out;
    float* out_attmap = out;                       // final att_map; attT mid-phase
    float* attT       = out;                       // [B,N,N]
    float* out_s      = out + 33554432;            // 524288
    float* out_c      = out + 34078720;            // 1048576
    float* out_gs     = out + 35127296;            // 64
    float* out_gc     = out + 35127360;            // 64
    float* pg0        = out + 33554432;            // GEMM partial s=0 (<=1,048,576)
    ushort* xc1bf     = (ushort*)(out + 34603008); // 1,048,576 ushorts
    float* Mp2        = out + 33554432;            // att2 stats partials (262144)
    float* Sp2        = out + 33816576;            // 262144

    const dim3 blk(256);
    const int ICS = 8;

    // global context s/c
    conv3x3_big<<<dim3(4, 4, B * ICS), blk, 0, stream>>>(xs, nullptr, w_g1, nullptr, cpart, 0, 64, 32, ICS);
    conv_combine<<<dim3((B * 32 * HW) / 256), blk, 0, stream>>>(cpart, g_g1, nullptr, t32, 32, ICS);
    gap_kernel<<<dim3(32, B), blk, 0, stream>>>(t32, gs_w, out_gs, 32, HW);
    conv3x3_big<<<dim3(4, 4, B * ICS), blk, 0, stream>>>(xc, nullptr, w_g2, nullptr, cpart, 0, 128, 32, ICS);
    conv_combine<<<dim3((B * 32 * HW) / 256), blk, 0, stream>>>(cpart, g_g2, nullptr, t32, 32, ICS);
    gap_kernel<<<dim3(32, B), blk, 0, stream>>>(t32, gc_w, out_gc, 32, HW);
    // local fusion convs + residual
    conv3x3_big<<<dim3(4, 8, B * ICS), blk, 0, stream>>>(xs, gs_w, w_ls, b_ls, cpart, 32, 64, 64, ICS);
    conv_combine<<<dim3((B * 64 * HW) / 256), blk, 0, stream>>>(cpart, g_ls, xs, xs1, 64, ICS);
    conv3x3_big<<<dim3(4, 16, B * ICS), blk, 0, stream>>>(xc, gc_w, w_lc, b_lc, cpart, 32, 128, 128, ICS);
    conv_combine<<<dim3((B * 128 * HW) / 256), blk, 0, stream>>>(cpart, g_lc, xc, xc1, 128, ICS);
    // attention features
    conv3x3_big<<<dim3(4, 4, B * ICS), blk, 0, stream>>>(xs1, nullptr, w_c1, nullptr, cpart, 0, 64, 32, ICS);
    conv_combine<<<dim3((B * 32 * HW) / 256), blk, 0, stream>>>(cpart, g_c1, nullptr, fs, 32, ICS);
    conv3x3_big<<<dim3(4, 4, B * ICS), blk, 0, stream>>>(xc1, nullptr, w_c2, nullptr, cpart, 0, 128, 32, ICS);
    conv_combine<<<dim3((B * 32 * HW) / 256), blk, 0, stream>>>(cpart, g_c2, nullptr, fc, 32, ICS);
    // att = fs^T fc  (+ attT into d_out scratch)
    att_gemm<<<dim3(16, 256, B), blk, 0, stream>>>(fs, fc, att, attT, N);
    // stats: column (Mc/Sc) and row (Mr/Sr)
    colstats_part<<<dim3(16, 16, B), blk, 0, stream>>>(att, Mp, Sp, N, 16);
    colstats_comb<<<dim3(16, B), blk, 0, stream>>>(Mp, Sp, Mc, Sc, N, 16);
    rowstats<<<dim3(N, B), blk, 0, stream>>>(att, Mr, Sr, N);
    // outc = xc1 @ rowsoftmax(att)^T  via MFMA
    to_bf16<<<dim3(1024), blk, 0, stream>>>(xc1, xc1bf, (long)B * 128 * N);
    sm_gemm_mfma<128><<<dim3(128, 2, B), blk, 0, stream>>>(xc1bf, att, Mr, pg0, pg1, N);
    sm_reduce2<128><<<dim3((B * 128 * N) / 256), blk, 0, stream>>>(pg0, pg1, Sr, outc_w, N);
    // outs = xs1 @ colsoftmax(att)  via MFMA on attT
    to_bf16<<<dim3(512), blk, 0, stream>>>(xs1, xs1bf, (long)B * 64 * N);
    sm_gemm_mfma<64><<<dim3(128, 2, B), blk, 0, stream>>>(xs1bf, attT, Mc, pg0, pg1, N);
    sm_reduce2<64><<<dim3((B * 64 * N) / 256), blk, 0, stream>>>(pg0, pg1, Sc, outs_w, N);
    // att2 = att + attT (streaming, in place) with fused column partial stats
    att2_stream<<<dim3(16, 32, B), blk, 0, stream>>>(att, attT, Mp2, Sp2, N);
    colstats_comb<<<dim3(16, B), blk, 0, stream>>>(Mp2, Sp2, M2, S2, N, 32);
    // fused att3 + 3x3 conv + BN + ReLU (overwrites attT region with final map)
    attmap_conv<<<dim3(64 * 1024, B), blk, 0, stream>>>(att, M2, S2, w_oa, g_oa, out_attmap, N);
    // output convs + residuals
    conv3x3_big<<<dim3(4, 8, B * ICS), blk, 0, stream>>>(outs_w, nullptr, w_o1, nullptr, cpart, 0, 64, 64, ICS);
    conv_combine<<<dim3((B * 64 * HW) / 256), blk, 0, stream>>>(cpart, g_o1, xs1, out_s, 64, ICS);
    conv3x3_big<<<dim3(4, 16, B * ICS), blk, 0, stream>>>(outc_w, nullptr, w_o2, nullptr, cpart, 0, 128, 128, ICS);
    conv_combine<<<dim3((B * 128 * HW) / 256), blk, 0, stream>>>(cpart, g_o2, xc1, out_c, 128, ICS);
}

// Round 7
// 916.160 us; speedup vs baseline: 1.1447x; 1.1447x over previous
//
#include <hip/hip_runtime.h>

// AGLI_5703716569604 — round 6: de-serialize stats/att2 chains + LDS-staged MFMA A.
// B=2, ch1=64, ch2=128, H=W=64, N=4096, att [B,4096,4096].

#define LB __launch_bounds__(256)

constexpr float BN_SCALE = 0.99999500003749968f; // 1/sqrt(1+1e-5)
constexpr float NEG_BIG  = -3.402823466e38f;

typedef __attribute__((ext_vector_type(8))) short short8v;
typedef __attribute__((ext_vector_type(4))) float f32x4;

__device__ __forceinline__ ushort bf16rne(float f) {
    unsigned u = __float_as_uint(f);
    unsigned r = (u + 0x7FFFu + ((u >> 16) & 1u)) >> 16;
    return (ushort)r;
}

// ---------------------------------------------------------------------------
// Stage one 34x34 halo tile (stride 35) for input channel image ib.
__device__ __forceinline__ void stage_tile(const float* __restrict__ ib,
                                           float* __restrict__ buf,
                                           int x0, int y0, int tid)
{
    #pragma unroll
    for (int r = 0; r < 5; ++r) {
        const int e = tid + r * 256;
        if (e < 1156) {
            const int hy = e / 34, hx = e % 34;
            const int yy = y0 + hy - 1, xx = x0 + hx - 1;
            float v = 0.f;
            if ((unsigned)yy < 64u && (unsigned)xx < 64u)
                v = ib[yy * 64 + xx];
            buf[hy * 35 + hx] = v;
        }
    }
}

// ---------------------------------------------------------------------------
// 3x3 conv partial over an ic-chunk (unchanged).
__global__ LB void conv3x3_big(
    const float* __restrict__ in, const float* __restrict__ gconst,
    const float* __restrict__ w, const float* __restrict__ bias,
    float* __restrict__ part, int Cg, int Cin, int Cout, int ICS)
{
    __shared__ float buf[2][34 * 35];
    __shared__ float wg[8][10];
    const int tid = threadIdx.x;
    const int tx = tid & 15, ty = tid >> 4;
    const int x0 = (blockIdx.x & 1) * 32, y0 = (blockIdx.x >> 1) * 32;
    const int oc0 = blockIdx.y * 8;
    const int b = blockIdx.z / ICS, s = blockIdx.z % ICS;
    const int chunk = Cin / ICS;
    const int ic0 = s * chunk;
    const int Ct = Cg + Cin;
    const int HW = 4096;

    float acc[8][4];
    #pragma unroll
    for (int oc = 0; oc < 8; ++oc)
        #pragma unroll
        for (int p = 0; p < 4; ++p) acc[oc][p] = 0.f;

    if (s == 0) {
        if (bias) {
            #pragma unroll
            for (int oc = 0; oc < 8; ++oc) {
                const float bv = bias[oc0 + oc];
                #pragma unroll
                for (int p = 0; p < 4; ++p) acc[oc][p] = bv;
            }
        }
        if (Cg > 0) {
            for (int e = tid; e < 72; e += 256) {
                const int oc = e / 9, k = e % 9;
                float sm = 0.f;
                for (int ic = 0; ic < Cg; ++ic)
                    sm += gconst[b * Cg + ic] * w[((long)(oc0 + oc) * Ct + ic) * 9 + k];
                wg[oc][k] = sm;
            }
            __syncthreads();
            #pragma unroll
            for (int k = 0; k < 9; ++k) {
                const int dy = k / 3 - 1, dx = k % 3 - 1;
                #pragma unroll
                for (int pr = 0; pr < 2; ++pr)
                    #pragma unroll
                    for (int pc = 0; pc < 2; ++pc) {
                        const int yy = y0 + ty * 2 + pr + dy;
                        const int xx = x0 + tx * 2 + pc + dx;
                        if ((unsigned)yy < 64u && (unsigned)xx < 64u) {
                            #pragma unroll
                            for (int oc = 0; oc < 8; ++oc)
                                acc[oc][pr * 2 + pc] += wg[oc][k];
                        }
                    }
            }
        }
    }

    const float* ib = in + ((long)b * Cin + ic0) * HW;
    stage_tile(ib, buf[0], x0, y0, tid);
    __syncthreads();
    int cur = 0;
    for (int i = 0; i < chunk; ++i) {
        if (i + 1 < chunk)
            stage_tile(ib + (long)(i + 1) * HW, buf[cur ^ 1], x0, y0, tid);
        float win[4][4];
        const float* bp = buf[cur] + (ty * 2) * 35 + tx * 2;
        #pragma unroll
        for (int r = 0; r < 4; ++r) {
            const float2 a = *(const float2*)&bp[r * 35];
            const float2 c = *(const float2*)&bp[r * 35 + 2];
            win[r][0] = a.x; win[r][1] = a.y; win[r][2] = c.x; win[r][3] = c.y;
        }
        const float* wq = w + ((long)oc0 * Ct + Cg + ic0 + i) * 9;
        #pragma unroll
        for (int oc = 0; oc < 8; ++oc) {
            const float* wo = wq + (long)oc * Ct * 9;
            #pragma unroll
            for (int dy = 0; dy < 3; ++dy)
                #pragma unroll
                for (int dx = 0; dx < 3; ++dx) {
                    const float wv = wo[dy * 3 + dx];
                    #pragma unroll
                    for (int pr = 0; pr < 2; ++pr)
                        #pragma unroll
                        for (int pc = 0; pc < 2; ++pc)
                            acc[oc][pr * 2 + pc] =
                                fmaf(wv, win[pr + dy][pc + dx], acc[oc][pr * 2 + pc]);
                }
        }
        __syncthreads();
        cur ^= 1;
    }

    #pragma unroll
    for (int oc = 0; oc < 8; ++oc) {
        #pragma unroll
        for (int pr = 0; pr < 2; ++pr) {
            float* q = part + (((long)s * 2 + b) * Cout + oc0 + oc) * (long)HW
                       + (y0 + ty * 2 + pr) * 64 + x0 + tx * 2;
            *(float2*)q = make_float2(acc[oc][pr * 2], acc[oc][pr * 2 + 1]);
        }
    }
}

// ---------------------------------------------------------------------------
__global__ LB void conv_combine(const float* __restrict__ part,
                                const float* __restrict__ bn,
                                const float* __restrict__ residual,
                                float* __restrict__ out,
                                int Cout, int ICS)
{
    const long idx = (long)blockIdx.x * 256 + threadIdx.x;
    const int hw = (int)(idx & 4095);
    const long t = idx >> 12;
    const int c = (int)(t % Cout);
    const int b = (int)(t / Cout);
    float v = 0.f;
    for (int s = 0; s < ICS; ++s)
        v += part[(((long)s * 2 + b) * Cout + c) * 4096 + hw];
    const float scale = bn[c] * BN_SCALE, beta = bn[Cout + c];
    float r = fmaxf(fmaf(v, scale, beta), 0.f);
    if (residual) r += residual[idx];
    out[idx] = r;
}

// ---------------------------------------------------------------------------
__global__ LB void gap_kernel(const float* __restrict__ in,
                              float* __restrict__ o1, float* __restrict__ o2,
                              int C, int HW)
{
    const int c = blockIdx.x, b = blockIdx.y;
    const float* p = in + ((long)b * C + c) * HW;
    float s = 0.f;
    for (int i = threadIdx.x; i < HW; i += 256) s += p[i];
    #pragma unroll
    for (int off = 32; off; off >>= 1) s += __shfl_down(s, off);
    __shared__ float red[4];
    if ((threadIdx.x & 63) == 0) red[threadIdx.x >> 6] = s;
    __syncthreads();
    if (threadIdx.x == 0) {
        const float t = (red[0] + red[1] + red[2] + red[3]) / (float)HW;
        o1[b * C + c] = t;
        o2[b * C + c] = t;
    }
}

// ---------------------------------------------------------------------------
// att[b,n,m] = sum_c fs[b,c,n] * fc[b,c,m], C=32. Also writes attT[b,m,n].
__global__ LB void att_gemm(const float* __restrict__ fs, const float* __restrict__ fc,
                            float* __restrict__ att, float* __restrict__ attT, int N)
{
    __shared__ float lfs[32][17];
    const int tid = threadIdx.x;
    const int m  = blockIdx.x * 256 + tid;
    const int n0 = blockIdx.y * 16;
    const int b  = blockIdx.z;
    for (int i = tid; i < 32 * 16; i += 256) {
        const int c = i >> 4, nn = i & 15;
        lfs[c][nn] = fs[((long)b * 32 + c) * N + n0 + nn];
    }
    __syncthreads();
    float acc[16];
    #pragma unroll
    for (int i = 0; i < 16; ++i) acc[i] = 0.f;
    const float* fcp = fc + (long)b * 32 * N + m;
    #pragma unroll
    for (int c = 0; c < 32; ++c) {
        const float f = fcp[(long)c * N];
        #pragma unroll
        for (int nn = 0; nn < 16; ++nn) acc[nn] = fmaf(lfs[c][nn], f, acc[nn]);
    }
    float* op = att + ((long)b * N + n0) * N + m;
    #pragma unroll
    for (int nn = 0; nn < 16; ++nn) op[(long)nn * N] = acc[nn];
    float* opT = attT + ((long)b * N + m) * N + n0;
    #pragma unroll
    for (int q = 0; q < 4; ++q)
        *(float4*)&opT[q * 4] = make_float4(acc[q*4], acc[q*4+1], acc[q*4+2], acc[q*4+3]);
}

// ---------------------------------------------------------------------------
// Column-wise online (max, sum-exp): block = 64 cols x 4 row-groups.
// grid: (N/64, S, B); per-thread chain = chunk/4; LDS merge.
__global__ LB void colstats_part(const float* __restrict__ att,
                                 float* __restrict__ Mp, float* __restrict__ Sp,
                                 int N, int S)
{
    __shared__ float lm[4][64], ls[4][64];
    const int c = threadIdx.x & 63, q = threadIdx.x >> 6;
    const int m = blockIdx.x * 64 + c;
    const int s = blockIdx.y, b = blockIdx.z;
    const int chunk = N / S;
    const float* p = att + (long)b * N * N + ((long)s * chunk + q) * N + m;
    float mx = NEG_BIG, sum = 0.f;
    for (int n = 0; n < chunk / 4; ++n) {
        const float v = p[(long)n * 4 * N];
        if (v > mx) { sum = sum * __expf(mx - v) + 1.f; mx = v; }
        else        { sum += __expf(v - mx); }
    }
    lm[q][c] = mx; ls[q][c] = sum;
    __syncthreads();
    if (q == 0) {
        float M = mx, Ss = sum;
        #pragma unroll
        for (int j = 1; j < 4; ++j) {
            const float m2 = lm[j][c], s2 = ls[j][c];
            const float mn = fmaxf(M, m2);
            Ss = Ss * __expf(M - mn) + s2 * __expf(m2 - mn);
            M = mn;
        }
        Mp[((long)b * S + s) * N + m] = M;
        Sp[((long)b * S + s) * N + m] = Ss;
    }
}

// grid: (N/256, B); combines S partial (max,sumexp) sets.
__global__ LB void colstats_comb(const float* __restrict__ Mp, const float* __restrict__ Sp,
                                 float* __restrict__ M, float* __restrict__ Sm,
                                 int N, int S)
{
    const int m = blockIdx.x * 256 + threadIdx.x;
    const int b = blockIdx.y;
    float mx = NEG_BIG, sum = 0.f;
    for (int s = 0; s < S; ++s) {
        const float m2 = Mp[((long)b * S + s) * N + m];
        const float s2 = Sp[((long)b * S + s) * N + m];
        const float mn = fmaxf(mx, m2);
        sum = sum * __expf(mx - mn) + s2 * __expf(m2 - mn);
        mx = mn;
    }
    M[(long)b * N + m]  = mx;
    Sm[(long)b * N + m] = sum;
}

// ---------------------------------------------------------------------------
// Row-wise (max, sum-exp). grid: (N, B), block 256
__global__ LB void rowstats(const float* __restrict__ att,
                            float* __restrict__ Mr, float* __restrict__ Sr, int N)
{
    const int n = blockIdx.x, b = blockIdx.y;
    const float* p = att + ((long)b * N + n) * N;
    float mx = NEG_BIG, sum = 0.f;
    for (int m = threadIdx.x; m < N; m += 256) {
        const float v = p[m];
        if (v > mx) { sum = sum * __expf(mx - v) + 1.f; mx = v; }
        else        { sum += __expf(v - mx); }
    }
    #pragma unroll
    for (int off = 32; off; off >>= 1) {
        const float m2 = __shfl_down(mx, off);
        const float s2 = __shfl_down(sum, off);
        const float mn = fmaxf(mx, m2);
        sum = sum * __expf(mx - mn) + s2 * __expf(m2 - mn);
        mx = mn;
    }
    __shared__ float rm[4], rs[4];
    const int lane = threadIdx.x & 63, wv = threadIdx.x >> 6;
    if (lane == 0) { rm[wv] = mx; rs[wv] = sum; }
    __syncthreads();
    if (threadIdx.x == 0) {
        mx = rm[0]; sum = rs[0];
        for (int w = 1; w < 4; ++w) {
            const float mn = fmaxf(mx, rm[w]);
            sum = sum * __expf(mx - mn) + rs[w] * __expf(rm[w] - mn);
            mx = mn;
        }
        Mr[(long)b * N + n] = mx;
        Sr[(long)b * N + n] = sum;
    }
}

// ---------------------------------------------------------------------------
// f32 -> bf16 conversion (vectorized).
__global__ LB void to_bf16(const float* __restrict__ in, ushort* __restrict__ out, long n)
{
    const long i = ((long)blockIdx.x * 256 + threadIdx.x) * 4;
    if (i >= n) return;
    const float4 v = *(const float4*)&in[i];
    ushort4 o;
    o.x = bf16rne(v.x); o.y = bf16rne(v.y); o.z = bf16rne(v.z); o.w = bf16rne(v.w);
    *(ushort4*)&out[i] = o;
}

// ---------------------------------------------------------------------------
// MFMA softmax-apply GEMM:
//   part_s[b,row,col] = sum_{k in chunk s} X[b,row,k] * exp(A[b,col,k] - Mv[b,col])
// A = att (outc) or attT (outs). X is bf16 [B][MROWS][N].
// grid: (N/32 col-tiles, 2 K-splits, B), block 256 = 4 waves.
// Both A-tile (MROWS x 32) and B-tile (32 x 32, exp-fused) staged in LDS.
template<int MROWS>
__global__ LB void sm_gemm_mfma(const ushort* __restrict__ Xbf,
                                const float* __restrict__ A,
                                const float* __restrict__ Mv,
                                float* __restrict__ p0, float* __restrict__ p1,
                                int N)
{
    constexpr int RT = MROWS / 32;          // row-tiles per wave (128->4, 64->2)
    constexpr int TPRA = 256 / MROWS;       // staging threads per A row
    __shared__ ushort ldsA[MROWS][40];      // [row][k] bf16, 80B stride
    __shared__ ushort ldsB[32][40];         // [col][k] bf16

    const int tid = threadIdx.x;
    const int wave = tid >> 6, lane = tid & 63;
    const int col0 = blockIdx.x * 32;
    const int s = blockIdx.y, b = blockIdx.z;
    const int K0 = s * (N / 2);

    const int scol = tid >> 3, sq = tid & 7;    // B staging: col, 4-k granule
    const int ar = tid / TPRA;                  // A staging row
    const int ak = (tid % TPRA) * (32 / TPRA);  // A staging k start
    const int wct = wave & 1;                   // col-16-tile
    const int wrh = wave >> 1;                  // row half
    const int fr = lane & 15, fg = lane >> 4;   // fragment row/col, k-group

    f32x4 acc[RT];
    #pragma unroll
    for (int i = 0; i < RT; ++i) acc[i] = (f32x4){0.f, 0.f, 0.f, 0.f};

    const float* ab = A + ((long)b * N + col0) * N;
    const ushort* xb = Xbf + (long)b * MROWS * N;
    const float mv = Mv[(long)b * N + col0 + scol];

    for (int k0 = K0; k0 < K0 + N / 2; k0 += 32) {
        __syncthreads();
        // stage A tile (coalesced 16B chunks)
        #pragma unroll
        for (int j = 0; j < 32 / TPRA; j += 8) {
            const short8v av = *(const short8v*)&xb[(long)ar * N + k0 + ak + j];
            *(short8v*)&ldsA[ar][ak + j] = av;
        }
        // stage B tile with fused exp
        const float4 v = *(const float4*)&ab[(long)scol * N + k0 + sq * 4];
        ushort4 bfv;
        bfv.x = bf16rne(__expf(v.x - mv));
        bfv.y = bf16rne(__expf(v.y - mv));
        bfv.z = bf16rne(__expf(v.z - mv));
        bfv.w = bf16rne(__expf(v.w - mv));
        *(ushort4*)&ldsB[scol][sq * 4] = bfv;
        __syncthreads();
        const short8v bfrag = *(const short8v*)&ldsB[wct * 16 + fr][8 * fg];
        #pragma unroll
        for (int rt = 0; rt < RT; ++rt) {
            const int row = wrh * (MROWS / 2) + rt * 16 + fr;
            const short8v afrag = *(const short8v*)&ldsA[row][8 * fg];
            acc[rt] = __builtin_amdgcn_mfma_f32_16x16x32_bf16(afrag, bfrag, acc[rt], 0, 0, 0);
        }
    }

    float* pp = (s == 0) ? p0 : p1;
    #pragma unroll
    for (int rt = 0; rt < RT; ++rt) {
        #pragma unroll
        for (int r = 0; r < 4; ++r) {
            const int row = wrh * (MROWS / 2) + rt * 16 + (lane >> 4) * 4 + r;
            const int col = col0 + wct * 16 + (lane & 15);
            pp[((long)b * MROWS + row) * N + col] = acc[rt][r];
        }
    }
}

// Sum 2 K-split partials and divide by per-column softmax denom.
template<int C>
__global__ LB void sm_reduce2(const float* __restrict__ p0, const float* __restrict__ p1,
                              const float* __restrict__ denom, float* __restrict__ outp, int N)
{
    const long idx = (long)blockIdx.x * 256 + threadIdx.x;
    const int m = (int)(idx & (long)(N - 1));
    const int b = (int)(idx / ((long)C * N));
    outp[idx] = (p0[idx] + p1[idx]) / denom[(long)b * N + m];
}

// ---------------------------------------------------------------------------
// Streaming att2 = att + attT (in place) with fused column partial stats.
// Block = 64 cols x 4 row-groups; chunk = 128 rows. grid: (N/64, 32, B).
__global__ LB void att2_stream(float* __restrict__ att, const float* __restrict__ attT,
                               float* __restrict__ Mp2, float* __restrict__ Sp2, int N)
{
    __shared__ float lm[4][64], ls[4][64];
    const int c = threadIdx.x & 63, q = threadIdx.x >> 6;
    const int col = blockIdx.x * 64 + c;
    const int y = blockIdx.y, b = blockIdx.z;
    const long base = (long)b * N * N + ((long)y * 128 + q) * N + col;
    float mx = NEG_BIG, sum = 0.f;
    for (int r = 0; r < 32; ++r) {
        const long off = base + (long)r * 4 * N;
        const float v = att[off] + attT[off];
        att[off] = v;
        if (v > mx) { sum = sum * __expf(mx - v) + 1.f; mx = v; }
        else        { sum += __expf(v - mx); }
    }
    lm[q][c] = mx; ls[q][c] = sum;
    __syncthreads();
    if (q == 0) {
        float M = mx, Ss = sum;
        #pragma unroll
        for (int j = 1; j < 4; ++j) {
            const float m2 = lm[j][c], s2 = ls[j][c];
            const float mn = fmaxf(M, m2);
            Ss = Ss * __expf(M - mn) + s2 * __expf(m2 - mn);
            M = mn;
        }
        Mp2[((long)b * 32 + y) * N + col] = M;
        Sp2[((long)b * 32 + y) * N + col] = Ss;
    }
}

// ---------------------------------------------------------------------------
// Fused: att3 = 2*exp(att2 - M2[m])/S2[m], then 3x3 conv + BN + ReLU.
__global__ LB void attmap_conv(const float* __restrict__ att2,
                               const float* __restrict__ M2, const float* __restrict__ S2,
                               const float* __restrict__ w, const float* __restrict__ g,
                               float* __restrict__ out, int N)
{
    __shared__ float t[6][67];
    const int tid = threadIdx.x;
    const int tx = tid & 63, ty = tid >> 6;
    const int x0 = (blockIdx.x & 63) * 64;
    const int y0 = (blockIdx.x >> 6) * 4;
    const int b = blockIdx.y;
    const float* ap = att2 + (long)b * N * N;
    const float* m2p = M2 + (long)b * N;
    const float* s2p = S2 + (long)b * N;
    for (int e = tid; e < 396; e += 256) {
        const int hy = e / 66, hx = e % 66;
        const int yy = y0 + hy - 1, xx = x0 + hx - 1;
        float v = 0.f;
        if ((unsigned)yy < (unsigned)N && (unsigned)xx < (unsigned)N)
            v = 2.f * __expf(ap[(long)yy * N + xx] - m2p[xx]) *
                __builtin_amdgcn_rcpf(s2p[xx]);
        t[hy][hx] = v;
    }
    __syncthreads();
    float acc = 0.f;
    #pragma unroll
    for (int k = 0; k < 9; ++k)
        acc = fmaf(w[k], t[ty + k / 3][tx + k % 3], acc);
    const float scale = g[0] * BN_SCALE, beta = g[1];
    out[(long)b * N * N + (long)(y0 + ty) * N + x0 + tx] =
        fmaxf(fmaf(acc, scale, beta), 0.f);
}

// ===========================================================================
extern "C" void kernel_launch(void* const* d_in, const int* in_sizes, int n_in,
                              void* d_out, int out_size, void* d_ws, size_t ws_size,
                              hipStream_t stream)
{
    const float* xs   = (const float*)d_in[0];
    const float* xc   = (const float*)d_in[1];
    const float* w_g1 = (const float*)d_in[2];
    const float* g_g1 = (const float*)d_in[3];
    const float* w_g2 = (const float*)d_in[4];
    const float* g_g2 = (const float*)d_in[5];
    const float* w_ls = (const float*)d_in[6];
    const float* b_ls = (const float*)d_in[7];
    const float* g_ls = (const float*)d_in[8];
    const float* w_lc = (const float*)d_in[9];
    const float* b_lc = (const float*)d_in[10];
    const float* g_lc = (const float*)d_in[11];
    const float* w_c1 = (const float*)d_in[12];
    const float* g_c1 = (const float*)d_in[13];
    const float* w_c2 = (const float*)d_in[14];
    const float* g_c2 = (const float*)d_in[15];
    const float* w_o1 = (const float*)d_in[16];
    const float* g_o1 = (const float*)d_in[17];
    const float* w_o2 = (const float*)d_in[18];
    const float* g_o2 = (const float*)d_in[19];
    const float* w_oa = (const float*)d_in[20];
    const float* g_oa = (const float*)d_in[21];

    const int B = 2, HW = 4096, N = 4096;

    // ---- workspace layout (float offsets) ----
    float* ws = (float*)d_ws;
    float* xs1    = ws;                       // 524288
    float* xc1    = ws + 524288;              // 1048576
    float* fs     = ws + 1572864;             // 262144
    float* fc     = ws + 1835008;             // 262144
    float* t32    = ws + 2097152;             // 262144
    float* outs_w = ws + 2359296;             // 524288
    float* outc_w = ws + 2883584;             // 1048576
    float* gs_w   = ws + 3932160;             // 64
    float* gc_w   = ws + 3932224;             // 64
    float* Mc     = ws + 3932288;             // 8192
    float* Sc     = ws + 3940480;             // 8192
    float* Mr     = ws + 3948672;             // 8192
    float* Sr     = ws + 3956864;             // 8192
    float* M2     = ws + 3965056;             // 8192
    float* S2     = ws + 3973248;             // 8192
    float* Mp     = ws + 3981440;             // 131072
    float* Sp     = ws + 4112512;             // 131072
    float* att    = ws + 4243584;             // 33554432
    float* cpart  = att;                      // conv partials alias (att dead then)
    float* pg1    = ws + 1572864;             // GEMM partial s=1 (fs..outs_w gap)
    ushort* xs1bf = (ushort*)(ws + 2097152);  // t32 slot

    // ---- d_out layout ----
    float* out = (float*)d_out;
    float* out_attmap = out;                       // final att_map; attT mid-phase
    float* attT       = out;                       // [B,N,N]
    float* out_s      = out + 33554432;            // 524288
    float* out_c      = out + 34078720;            // 1048576
    float* out_gs     = out + 35127296;            // 64
    float* out_gc     = out + 35127360;            // 64
    float* pg0        = out + 33554432;            // GEMM partial s=0
    ushort* xc1bf     = (ushort*)(out + 34603008); // 1,048,576 ushorts
    float* Mp2        = out + 33554432;            // att2 stats partials [B,32,N]
    float* Sp2        = out + 33816576;

    const dim3 blk(256);
    const int ICS = 8;

    // global context s/c
    conv3x3_big<<<dim3(4, 4, B * ICS), blk, 0, stream>>>(xs, nullptr, w_g1, nullptr, cpart, 0, 64, 32, ICS);
    conv_combine<<<dim3((B * 32 * HW) / 256), blk, 0, stream>>>(cpart, g_g1, nullptr, t32, 32, ICS);
    gap_kernel<<<dim3(32, B), blk, 0, stream>>>(t32, gs_w, out_gs, 32, HW);
    conv3x3_big<<<dim3(4, 4, B * ICS), blk, 0, stream>>>(xc, nullptr, w_g2, nullptr, cpart, 0, 128, 32, ICS);
    conv_combine<<<dim3((B * 32 * HW) / 256), blk, 0, stream>>>(cpart, g_g2, nullptr, t32, 32, ICS);
    gap_kernel<<<dim3(32, B), blk, 0, stream>>>(t32, gc_w, out_gc, 32, HW);
    // local fusion convs + residual
    conv3x3_big<<<dim3(4, 8, B * ICS), blk, 0, stream>>>(xs, gs_w, w_ls, b_ls, cpart, 32, 64, 64, ICS);
    conv_combine<<<dim3((B * 64 * HW) / 256), blk, 0, stream>>>(cpart, g_ls, xs, xs1, 64, ICS);
    conv3x3_big<<<dim3(4, 16, B * ICS), blk, 0, stream>>>(xc, gc_w, w_lc, b_lc, cpart, 32, 128, 128, ICS);
    conv_combine<<<dim3((B * 128 * HW) / 256), blk, 0, stream>>>(cpart, g_lc, xc, xc1, 128, ICS);
    // attention features
    conv3x3_big<<<dim3(4, 4, B * ICS), blk, 0, stream>>>(xs1, nullptr, w_c1, nullptr, cpart, 0, 64, 32, ICS);
    conv_combine<<<dim3((B * 32 * HW) / 256), blk, 0, stream>>>(cpart, g_c1, nullptr, fs, 32, ICS);
    conv3x3_big<<<dim3(4, 4, B * ICS), blk, 0, stream>>>(xc1, nullptr, w_c2, nullptr, cpart, 0, 128, 32, ICS);
    conv_combine<<<dim3((B * 32 * HW) / 256), blk, 0, stream>>>(cpart, g_c2, nullptr, fc, 32, ICS);
    // att = fs^T fc  (+ attT into d_out scratch)
    att_gemm<<<dim3(16, 256, B), blk, 0, stream>>>(fs, fc, att, attT, N);
    // stats: column (Mc/Sc) and row (Mr/Sr)
    colstats_part<<<dim3(64, 16, B), blk, 0, stream>>>(att, Mp, Sp, N, 16);
    colstats_comb<<<dim3(16, B), blk, 0, stream>>>(Mp, Sp, Mc, Sc, N, 16);
    rowstats<<<dim3(N, B), blk, 0, stream>>>(att, Mr, Sr, N);
    // outc = xc1 @ rowsoftmax(att)^T  via MFMA
    to_bf16<<<dim3(1024), blk, 0, stream>>>(xc1, xc1bf, (long)B * 128 * N);
    sm_gemm_mfma<128><<<dim3(128, 2, B), blk, 0, stream>>>(xc1bf, att, Mr, pg0, pg1, N);
    sm_reduce2<128><<<dim3((B * 128 * N) / 256), blk, 0, stream>>>(pg0, pg1, Sr, outc_w, N);
    // outs = xs1 @ colsoftmax(att)  via MFMA on attT
    to_bf16<<<dim3(512), blk, 0, stream>>>(xs1, xs1bf, (long)B * 64 * N);
    sm_gemm_mfma<64><<<dim3(128, 2, B), blk, 0, stream>>>(xs1bf, attT, Mc, pg0, pg1, N);
    sm_reduce2<64><<<dim3((B * 64 * N) / 256), blk, 0, stream>>>(pg0, pg1, Sc, outs_w, N);
    // att2 = att + attT (streaming, in place) with fused column partial stats
    att2_stream<<<dim3(64, 32, B), blk, 0, stream>>>(att, attT, Mp2, Sp2, N);
    colstats_comb<<<dim3(16, B), blk, 0, stream>>>(Mp2, Sp2, M2, S2, N, 32);
    // fused att3 + 3x3 conv + BN + ReLU (overwrites attT region with final map)
    attmap_conv<<<dim3(64 * 1024, B), blk, 0, stream>>>(att, M2, S2, w_oa, g_oa, out_attmap, N);
    // output convs + residuals
    conv3x3_big<<<dim3(4, 8, B * ICS), blk, 0, stream>>>(outs_w, nullptr, w_o1, nullptr, cpart, 0, 64, 64, ICS);
    conv_combine<<<dim3((B * 64 * HW) / 256), blk, 0, stream>>>(cpart, g_o1, xs1, out_s, 64, ICS);
    conv3x3_big<<<dim3(4, 16, B * ICS), blk, 0, stream>>>(outc_w, nullptr, w_o2, nullptr, cpart, 0, 128, 128, ICS);
    conv_combine<<<dim3((B * 128 * HW) / 256), blk, 0, stream>>>(cpart, g_o2, xc1, out_c, 128, ICS);
}

// Round 8
// 887.599 us; speedup vs baseline: 1.1815x; 1.0322x over previous
//
#include <hip/hip_runtime.h>

// AGLI_5703716569604 — round 7: exp2-folded attmap_conv (64x32 tile) + C2L precompute.
// B=2, ch1=64, ch2=128, H=W=64, N=4096, att [B,4096,4096].

#define LB __launch_bounds__(256)

constexpr float BN_SCALE = 0.99999500003749968f; // 1/sqrt(1+1e-5)
constexpr float NEG_BIG  = -3.402823466e38f;
constexpr float LOG2E    = 1.4426950408889634f;
constexpr float LN2      = 0.6931471805599453f;

typedef __attribute__((ext_vector_type(8))) short short8v;
typedef __attribute__((ext_vector_type(4))) float f32x4;

__device__ __forceinline__ ushort bf16rne(float f) {
    unsigned u = __float_as_uint(f);
    unsigned r = (u + 0x7FFFu + ((u >> 16) & 1u)) >> 16;
    return (ushort)r;
}

// ---------------------------------------------------------------------------
// Stage one 34x34 halo tile (stride 35) for input channel image ib.
__device__ __forceinline__ void stage_tile(const float* __restrict__ ib,
                                           float* __restrict__ buf,
                                           int x0, int y0, int tid)
{
    #pragma unroll
    for (int r = 0; r < 5; ++r) {
        const int e = tid + r * 256;
        if (e < 1156) {
            const int hy = e / 34, hx = e % 34;
            const int yy = y0 + hy - 1, xx = x0 + hx - 1;
            float v = 0.f;
            if ((unsigned)yy < 64u && (unsigned)xx < 64u)
                v = ib[yy * 64 + xx];
            buf[hy * 35 + hx] = v;
        }
    }
}

// ---------------------------------------------------------------------------
// 3x3 conv partial over an ic-chunk (unchanged).
__global__ LB void conv3x3_big(
    const float* __restrict__ in, const float* __restrict__ gconst,
    const float* __restrict__ w, const float* __restrict__ bias,
    float* __restrict__ part, int Cg, int Cin, int Cout, int ICS)
{
    __shared__ float buf[2][34 * 35];
    __shared__ float wg[8][10];
    const int tid = threadIdx.x;
    const int tx = tid & 15, ty = tid >> 4;
    const int x0 = (blockIdx.x & 1) * 32, y0 = (blockIdx.x >> 1) * 32;
    const int oc0 = blockIdx.y * 8;
    const int b = blockIdx.z / ICS, s = blockIdx.z % ICS;
    const int chunk = Cin / ICS;
    const int ic0 = s * chunk;
    const int Ct = Cg + Cin;
    const int HW = 4096;

    float acc[8][4];
    #pragma unroll
    for (int oc = 0; oc < 8; ++oc)
        #pragma unroll
        for (int p = 0; p < 4; ++p) acc[oc][p] = 0.f;

    if (s == 0) {
        if (bias) {
            #pragma unroll
            for (int oc = 0; oc < 8; ++oc) {
                const float bv = bias[oc0 + oc];
                #pragma unroll
                for (int p = 0; p < 4; ++p) acc[oc][p] = bv;
            }
        }
        if (Cg > 0) {
            for (int e = tid; e < 72; e += 256) {
                const int oc = e / 9, k = e % 9;
                float sm = 0.f;
                for (int ic = 0; ic < Cg; ++ic)
                    sm += gconst[b * Cg + ic] * w[((long)(oc0 + oc) * Ct + ic) * 9 + k];
                wg[oc][k] = sm;
            }
            __syncthreads();
            #pragma unroll
            for (int k = 0; k < 9; ++k) {
                const int dy = k / 3 - 1, dx = k % 3 - 1;
                #pragma unroll
                for (int pr = 0; pr < 2; ++pr)
                    #pragma unroll
                    for (int pc = 0; pc < 2; ++pc) {
                        const int yy = y0 + ty * 2 + pr + dy;
                        const int xx = x0 + tx * 2 + pc + dx;
                        if ((unsigned)yy < 64u && (unsigned)xx < 64u) {
                            #pragma unroll
                            for (int oc = 0; oc < 8; ++oc)
                                acc[oc][pr * 2 + pc] += wg[oc][k];
                        }
                    }
            }
        }
    }

    const float* ib = in + ((long)b * Cin + ic0) * HW;
    stage_tile(ib, buf[0], x0, y0, tid);
    __syncthreads();
    int cur = 0;
    for (int i = 0; i < chunk; ++i) {
        if (i + 1 < chunk)
            stage_tile(ib + (long)(i + 1) * HW, buf[cur ^ 1], x0, y0, tid);
        float win[4][4];
        const float* bp = buf[cur] + (ty * 2) * 35 + tx * 2;
        #pragma unroll
        for (int r = 0; r < 4; ++r) {
            const float2 a = *(const float2*)&bp[r * 35];
            const float2 c = *(const float2*)&bp[r * 35 + 2];
            win[r][0] = a.x; win[r][1] = a.y; win[r][2] = c.x; win[r][3] = c.y;
        }
        const float* wq = w + ((long)oc0 * Ct + Cg + ic0 + i) * 9;
        #pragma unroll
        for (int oc = 0; oc < 8; ++oc) {
            const float* wo = wq + (long)oc * Ct * 9;
            #pragma unroll
            for (int dy = 0; dy < 3; ++dy)
                #pragma unroll
                for (int dx = 0; dx < 3; ++dx) {
                    const float wv = wo[dy * 3 + dx];
                    #pragma unroll
                    for (int pr = 0; pr < 2; ++pr)
                        #pragma unroll
                        for (int pc = 0; pc < 2; ++pc)
                            acc[oc][pr * 2 + pc] =
                                fmaf(wv, win[pr + dy][pc + dx], acc[oc][pr * 2 + pc]);
                }
        }
        __syncthreads();
        cur ^= 1;
    }

    #pragma unroll
    for (int oc = 0; oc < 8; ++oc) {
        #pragma unroll
        for (int pr = 0; pr < 2; ++pr) {
            float* q = part + (((long)s * 2 + b) * Cout + oc0 + oc) * (long)HW
                       + (y0 + ty * 2 + pr) * 64 + x0 + tx * 2;
            *(float2*)q = make_float2(acc[oc][pr * 2], acc[oc][pr * 2 + 1]);
        }
    }
}

// ---------------------------------------------------------------------------
__global__ LB void conv_combine(const float* __restrict__ part,
                                const float* __restrict__ bn,
                                const float* __restrict__ residual,
                                float* __restrict__ out,
                                int Cout, int ICS)
{
    const long idx = (long)blockIdx.x * 256 + threadIdx.x;
    const int hw = (int)(idx & 4095);
    const long t = idx >> 12;
    const int c = (int)(t % Cout);
    const int b = (int)(t / Cout);
    float v = 0.f;
    for (int s = 0; s < ICS; ++s)
        v += part[(((long)s * 2 + b) * Cout + c) * 4096 + hw];
    const float scale = bn[c] * BN_SCALE, beta = bn[Cout + c];
    float r = fmaxf(fmaf(v, scale, beta), 0.f);
    if (residual) r += residual[idx];
    out[idx] = r;
}

// ---------------------------------------------------------------------------
__global__ LB void gap_kernel(const float* __restrict__ in,
                              float* __restrict__ o1, float* __restrict__ o2,
                              int C, int HW)
{
    const int c = blockIdx.x, b = blockIdx.y;
    const float* p = in + ((long)b * C + c) * HW;
    float s = 0.f;
    for (int i = threadIdx.x; i < HW; i += 256) s += p[i];
    #pragma unroll
    for (int off = 32; off; off >>= 1) s += __shfl_down(s, off);
    __shared__ float red[4];
    if ((threadIdx.x & 63) == 0) red[threadIdx.x >> 6] = s;
    __syncthreads();
    if (threadIdx.x == 0) {
        const float t = (red[0] + red[1] + red[2] + red[3]) / (float)HW;
        o1[b * C + c] = t;
        o2[b * C + c] = t;
    }
}

// ---------------------------------------------------------------------------
// att[b,n,m] = sum_c fs[b,c,n] * fc[b,c,m], C=32. Also writes attT[b,m,n].
__global__ LB void att_gemm(const float* __restrict__ fs, const float* __restrict__ fc,
                            float* __restrict__ att, float* __restrict__ attT, int N)
{
    __shared__ float lfs[32][17];
    const int tid = threadIdx.x;
    const int m  = blockIdx.x * 256 + tid;
    const int n0 = blockIdx.y * 16;
    const int b  = blockIdx.z;
    for (int i = tid; i < 32 * 16; i += 256) {
        const int c = i >> 4, nn = i & 15;
        lfs[c][nn] = fs[((long)b * 32 + c) * N + n0 + nn];
    }
    __syncthreads();
    float acc[16];
    #pragma unroll
    for (int i = 0; i < 16; ++i) acc[i] = 0.f;
    const float* fcp = fc + (long)b * 32 * N + m;
    #pragma unroll
    for (int c = 0; c < 32; ++c) {
        const float f = fcp[(long)c * N];
        #pragma unroll
        for (int nn = 0; nn < 16; ++nn) acc[nn] = fmaf(lfs[c][nn], f, acc[nn]);
    }
    float* op = att + ((long)b * N + n0) * N + m;
    #pragma unroll
    for (int nn = 0; nn < 16; ++nn) op[(long)nn * N] = acc[nn];
    float* opT = attT + ((long)b * N + m) * N + n0;
    #pragma unroll
    for (int q = 0; q < 4; ++q)
        *(float4*)&opT[q * 4] = make_float4(acc[q*4], acc[q*4+1], acc[q*4+2], acc[q*4+3]);
}

// ---------------------------------------------------------------------------
// Column-wise online (max, sum-exp): block = 64 cols x 4 row-groups.
__global__ LB void colstats_part(const float* __restrict__ att,
                                 float* __restrict__ Mp, float* __restrict__ Sp,
                                 int N, int S)
{
    __shared__ float lm[4][64], ls[4][64];
    const int c = threadIdx.x & 63, q = threadIdx.x >> 6;
    const int m = blockIdx.x * 64 + c;
    const int s = blockIdx.y, b = blockIdx.z;
    const int chunk = N / S;
    const float* p = att + (long)b * N * N + ((long)s * chunk + q) * N + m;
    float mx = NEG_BIG, sum = 0.f;
    for (int n = 0; n < chunk / 4; ++n) {
        const float v = p[(long)n * 4 * N];
        if (v > mx) { sum = sum * __expf(mx - v) + 1.f; mx = v; }
        else        { sum += __expf(v - mx); }
    }
    lm[q][c] = mx; ls[q][c] = sum;
    __syncthreads();
    if (q == 0) {
        float M = mx, Ss = sum;
        #pragma unroll
        for (int j = 1; j < 4; ++j) {
            const float m2 = lm[j][c], s2 = ls[j][c];
            const float mn = fmaxf(M, m2);
            Ss = Ss * __expf(M - mn) + s2 * __expf(m2 - mn);
            M = mn;
        }
        Mp[((long)b * S + s) * N + m] = M;
        Sp[((long)b * S + s) * N + m] = Ss;
    }
}

// grid: (N/256, B); combines S partial sets. Optionally writes C2L for attmap.
__global__ LB void colstats_comb(const float* __restrict__ Mp, const float* __restrict__ Sp,
                                 float* __restrict__ M, float* __restrict__ Sm,
                                 float* __restrict__ C2L, int N, int S)
{
    const int m = blockIdx.x * 256 + threadIdx.x;
    const int b = blockIdx.y;
    float mx = NEG_BIG, sum = 0.f;
    for (int s = 0; s < S; ++s) {
        const float m2 = Mp[((long)b * S + s) * N + m];
        const float s2 = Sp[((long)b * S + s) * N + m];
        const float mn = fmaxf(mx, m2);
        sum = sum * __expf(mx - mn) + s2 * __expf(m2 - mn);
        mx = mn;
    }
    M[(long)b * N + m]  = mx;
    Sm[(long)b * N + m] = sum;
    if (C2L) C2L[(long)b * N + m] = (mx - LN2 + __logf(sum)) * LOG2E;
}

// ---------------------------------------------------------------------------
// Row-wise (max, sum-exp). grid: (N, B), block 256
__global__ LB void rowstats(const float* __restrict__ att,
                            float* __restrict__ Mr, float* __restrict__ Sr, int N)
{
    const int n = blockIdx.x, b = blockIdx.y;
    const float* p = att + ((long)b * N + n) * N;
    float mx = NEG_BIG, sum = 0.f;
    for (int m = threadIdx.x; m < N; m += 256) {
        const float v = p[m];
        if (v > mx) { sum = sum * __expf(mx - v) + 1.f; mx = v; }
        else        { sum += __expf(v - mx); }
    }
    #pragma unroll
    for (int off = 32; off; off >>= 1) {
        const float m2 = __shfl_down(mx, off);
        const float s2 = __shfl_down(sum, off);
        const float mn = fmaxf(mx, m2);
        sum = sum * __expf(mx - mn) + s2 * __expf(m2 - mn);
        mx = mn;
    }
    __shared__ float rm[4], rs[4];
    const int lane = threadIdx.x & 63, wv = threadIdx.x >> 6;
    if (lane == 0) { rm[wv] = mx; rs[wv] = sum; }
    __syncthreads();
    if (threadIdx.x == 0) {
        mx = rm[0]; sum = rs[0];
        for (int w = 1; w < 4; ++w) {
            const float mn = fmaxf(mx, rm[w]);
            sum = sum * __expf(mx - mn) + rs[w] * __expf(rm[w] - mn);
            mx = mn;
        }
        Mr[(long)b * N + n] = mx;
        Sr[(long)b * N + n] = sum;
    }
}

// ---------------------------------------------------------------------------
// f32 -> bf16 conversion (vectorized).
__global__ LB void to_bf16(const float* __restrict__ in, ushort* __restrict__ out, long n)
{
    const long i = ((long)blockIdx.x * 256 + threadIdx.x) * 4;
    if (i >= n) return;
    const float4 v = *(const float4*)&in[i];
    ushort4 o;
    o.x = bf16rne(v.x); o.y = bf16rne(v.y); o.z = bf16rne(v.z); o.w = bf16rne(v.w);
    *(ushort4*)&out[i] = o;
}

// ---------------------------------------------------------------------------
// MFMA softmax-apply GEMM:
//   part_s[b,row,col] = sum_{k in chunk s} X[b,row,k] * exp(A[b,col,k] - Mv[b,col])
template<int MROWS>
__global__ LB void sm_gemm_mfma(const ushort* __restrict__ Xbf,
                                const float* __restrict__ A,
                                const float* __restrict__ Mv,
                                float* __restrict__ p0, float* __restrict__ p1,
                                int N)
{
    constexpr int RT = MROWS / 32;
    constexpr int TPRA = 256 / MROWS;
    __shared__ ushort ldsA[MROWS][40];
    __shared__ ushort ldsB[32][40];

    const int tid = threadIdx.x;
    const int wave = tid >> 6, lane = tid & 63;
    const int col0 = blockIdx.x * 32;
    const int s = blockIdx.y, b = blockIdx.z;
    const int K0 = s * (N / 2);

    const int scol = tid >> 3, sq = tid & 7;
    const int ar = tid / TPRA;
    const int ak = (tid % TPRA) * (32 / TPRA);
    const int wct = wave & 1;
    const int wrh = wave >> 1;
    const int fr = lane & 15, fg = lane >> 4;

    f32x4 acc[RT];
    #pragma unroll
    for (int i = 0; i < RT; ++i) acc[i] = (f32x4){0.f, 0.f, 0.f, 0.f};

    const float* ab = A + ((long)b * N + col0) * N;
    const ushort* xb = Xbf + (long)b * MROWS * N;
    const float mvl = Mv[(long)b * N + col0 + scol] * LOG2E;

    for (int k0 = K0; k0 < K0 + N / 2; k0 += 32) {
        __syncthreads();
        #pragma unroll
        for (int j = 0; j < 32 / TPRA; j += 8) {
            const short8v av = *(const short8v*)&xb[(long)ar * N + k0 + ak + j];
            *(short8v*)&ldsA[ar][ak + j] = av;
        }
        const float4 v = *(const float4*)&ab[(long)scol * N + k0 + sq * 4];
        ushort4 bfv;
        bfv.x = bf16rne(exp2f(fmaf(v.x, LOG2E, -mvl)));
        bfv.y = bf16rne(exp2f(fmaf(v.y, LOG2E, -mvl)));
        bfv.z = bf16rne(exp2f(fmaf(v.z, LOG2E, -mvl)));
        bfv.w = bf16rne(exp2f(fmaf(v.w, LOG2E, -mvl)));
        *(ushort4*)&ldsB[scol][sq * 4] = bfv;
        __syncthreads();
        const short8v bfrag = *(const short8v*)&ldsB[wct * 16 + fr][8 * fg];
        #pragma unroll
        for (int rt = 0; rt < RT; ++rt) {
            const int row = wrh * (MROWS / 2) + rt * 16 + fr;
            const short8v afrag = *(const short8v*)&ldsA[row][8 * fg];
            acc[rt] = __builtin_amdgcn_mfma_f32_16x16x32_bf16(afrag, bfrag, acc[rt], 0, 0, 0);
        }
    }

    float* pp = (s == 0) ? p0 : p1;
    #pragma unroll
    for (int rt = 0; rt < RT; ++rt) {
        #pragma unroll
        for (int r = 0; r < 4; ++r) {
            const int row = wrh * (MROWS / 2) + rt * 16 + (lane >> 4) * 4 + r;
            const int col = col0 + wct * 16 + (lane & 15);
            pp[((long)b * MROWS + row) * N + col] = acc[rt][r];
        }
    }
}

// Sum 2 K-split partials and divide by per-column softmax denom.
template<int C>
__global__ LB void sm_reduce2(const float* __restrict__ p0, const float* __restrict__ p1,
                              const float* __restrict__ denom, float* __restrict__ outp, int N)
{
    const long idx = (long)blockIdx.x * 256 + threadIdx.x;
    const int m = (int)(idx & (long)(N - 1));
    const int b = (int)(idx / ((long)C * N));
    outp[idx] = (p0[idx] + p1[idx]) / denom[(long)b * N + m];
}

// ---------------------------------------------------------------------------
// Streaming att2 = att + attT (in place) with fused column partial stats.
__global__ LB void att2_stream(float* __restrict__ att, const float* __restrict__ attT,
                               float* __restrict__ Mp2, float* __restrict__ Sp2, int N)
{
    __shared__ float lm[4][64], ls[4][64];
    const int c = threadIdx.x & 63, q = threadIdx.x >> 6;
    const int col = blockIdx.x * 64 + c;
    const int y = blockIdx.y, b = blockIdx.z;
    const long base = (long)b * N * N + ((long)y * 128 + q) * N + col;
    float mx = NEG_BIG, sum = 0.f;
    for (int r = 0; r < 32; ++r) {
        const long off = base + (long)r * 4 * N;
        const float v = att[off] + attT[off];
        att[off] = v;
        if (v > mx) { sum = sum * __expf(mx - v) + 1.f; mx = v; }
        else        { sum += __expf(v - mx); }
    }
    lm[q][c] = mx; ls[q][c] = sum;
    __syncthreads();
    if (q == 0) {
        float M = mx, Ss = sum;
        #pragma unroll
        for (int j = 1; j < 4; ++j) {
            const float m2 = lm[j][c], s2 = ls[j][c];
            const float mn = fmaxf(M, m2);
            Ss = Ss * __expf(M - mn) + s2 * __expf(m2 - mn);
            M = mn;
        }
        Mp2[((long)b * 32 + y) * N + col] = M;
        Sp2[((long)b * 32 + y) * N + col] = Ss;
    }
}

// ---------------------------------------------------------------------------
// Fused: att3 = exp2(v*log2e - C2L[m]) (== 2*exp(v-M2)/S2), then 3x3 conv+BN+ReLU.
// Tile 64x32 per block (halo 66x34), 8 outputs/thread. grid: (8192, B).
__global__ LB void attmap_conv(const float* __restrict__ att2,
                               const float* __restrict__ C2L,
                               const float* __restrict__ w, const float* __restrict__ g,
                               float* __restrict__ out, int N)
{
    __shared__ float t[34][68];
    __shared__ float ldc[66];
    const int tid = threadIdx.x;
    const int tx = tid & 63, ty = tid >> 6;
    const int x0 = (blockIdx.x & 63) * 64;
    const int y0 = (blockIdx.x >> 6) * 32;
    const int b = blockIdx.y;
    const float* ap = att2 + (long)b * N * N;
    const float* cp = C2L + (long)b * N;

    if (tid < 66) {
        const int xx = x0 + tid - 1;
        ldc[tid] = ((unsigned)xx < (unsigned)N) ? cp[xx] : 0.f;
    }
    __syncthreads();

    #pragma unroll
    for (int r = 0; r < 9; ++r) {
        const int e = tid + r * 256;
        if (e < 2244) {
            const int hy = e / 66, hx = e % 66;
            const int yy = y0 + hy - 1, xx = x0 + hx - 1;
            float v = 0.f;
            if ((unsigned)yy < (unsigned)N && (unsigned)xx < (unsigned)N)
                v = exp2f(fmaf(ap[(long)yy * N + xx], LOG2E, -ldc[hx]));
            t[hy][hx] = v;
        }
    }
    __syncthreads();

    const float scale = g[0] * BN_SCALE, beta = g[1];
    float* ob = out + (long)b * N * N + (long)y0 * N + x0 + tx;
    #pragma unroll
    for (int rr = 0; rr < 8; ++rr) {
        const int ly = ty * 8 + rr;
        float acc = 0.f;
        #pragma unroll
        for (int ky = 0; ky < 3; ++ky)
            #pragma unroll
            for (int kx = 0; kx < 3; ++kx)
                acc = fmaf(w[ky * 3 + kx], t[ly + ky][tx + kx], acc);
        ob[(long)ly * N] = fmaxf(fmaf(acc, scale, beta), 0.f);
    }
}

// ===========================================================================
extern "C" void kernel_launch(void* const* d_in, const int* in_sizes, int n_in,
                              void* d_out, int out_size, void* d_ws, size_t ws_size,
                              hipStream_t stream)
{
    const float* xs   = (const float*)d_in[0];
    const float* xc   = (const float*)d_in[1];
    const float* w_g1 = (const float*)d_in[2];
    const float* g_g1 = (const float*)d_in[3];
    const float* w_g2 = (const float*)d_in[4];
    const float* g_g2 = (const float*)d_in[5];
    const float* w_ls = (const float*)d_in[6];
    const float* b_ls = (const float*)d_in[7];
    const float* g_ls = (const float*)d_in[8];
    const float* w_lc = (const float*)d_in[9];
    const float* b_lc = (const float*)d_in[10];
    const float* g_lc = (const float*)d_in[11];
    const float* w_c1 = (const float*)d_in[12];
    const float* g_c1 = (const float*)d_in[13];
    const float* w_c2 = (const float*)d_in[14];
    const float* g_c2 = (const float*)d_in[15];
    const float* w_o1 = (const float*)d_in[16];
    const float* g_o1 = (const float*)d_in[17];
    const float* w_o2 = (const float*)d_in[18];
    const float* g_o2 = (const float*)d_in[19];
    const float* w_oa = (const float*)d_in[20];
    const float* g_oa = (const float*)d_in[21];

    const int B = 2, HW = 4096, N = 4096;

    // ---- workspace layout (float offsets) ----
    float* ws = (float*)d_ws;
    float* xs1    = ws;                       // 524288
    float* xc1    = ws + 524288;              // 1048576
    float* fs     = ws + 1572864;             // 262144
    float* fc     = ws + 1835008;             // 262144
    float* t32    = ws + 2097152;             // 262144
    float* outs_w = ws + 2359296;             // 524288
    float* outc_w = ws + 2883584;             // 1048576
    float* gs_w   = ws + 3932160;             // 64
    float* gc_w   = ws + 3932224;             // 64
    float* Mc     = ws + 3932288;             // 8192
    float* Sc     = ws + 3940480;             // 8192
    float* Mr     = ws + 3948672;             // 8192
    float* Sr     = ws + 3956864;             // 8192
    float* M2     = ws + 3965056;             // 8192
    float* S2     = ws + 3973248;             // 8192
    float* Mp     = ws + 3981440;             // 131072
    float* C2L    = ws + 3981440;             // 8192 (reuses dead Mp slot)
    float* Sp     = ws + 4112512;             // 131072
    float* att    = ws + 4243584;             // 33554432
    float* cpart  = att;                      // conv partials alias
    float* pg1    = ws + 1572864;             // GEMM partial s=1 (fs..outs_w gap)
    ushort* xs1bf = (ushort*)(ws + 2097152);  // t32 slot

    // ---- d_out layout ----
    float* out = (float*)d_out;
    float* out_attmap = out;                       // final att_map; attT mid-phase
    float* attT       = out;                       // [B,N,N]
    float* out_s      = out + 33554432;            // 524288
    float* out_c      = out + 34078720;            // 1048576
    float* out_gs     = out + 35127296;            // 64
    float* out_gc     = out + 35127360;            // 64
    float* pg0        = out + 33554432;            // GEMM partial s=0
    ushort* xc1bf     = (ushort*)(out + 34603008); // 1,048,576 ushorts
    float* Mp2        = out + 33554432;            // att2 stats partials [B,32,N]
    float* Sp2        = out + 33816576;

    const dim3 blk(256);
    const int ICS = 8;

    // global context s/c
    conv3x3_big<<<dim3(4, 4, B * ICS), blk, 0, stream>>>(xs, nullptr, w_g1, nullptr, cpart, 0, 64, 32, ICS);
    conv_combine<<<dim3((B * 32 * HW) / 256), blk, 0, stream>>>(cpart, g_g1, nullptr, t32, 32, ICS);
    gap_kernel<<<dim3(32, B), blk, 0, stream>>>(t32, gs_w, out_gs, 32, HW);
    conv3x3_big<<<dim3(4, 4, B * ICS), blk, 0, stream>>>(xc, nullptr, w_g2, nullptr, cpart, 0, 128, 32, ICS);
    conv_combine<<<dim3((B * 32 * HW) / 256), blk, 0, stream>>>(cpart, g_g2, nullptr, t32, 32, ICS);
    gap_kernel<<<dim3(32, B), blk, 0, stream>>>(t32, gc_w, out_gc, 32, HW);
    // local fusion convs + residual
    conv3x3_big<<<dim3(4, 8, B * ICS), blk, 0, stream>>>(xs, gs_w, w_ls, b_ls, cpart, 32, 64, 64, ICS);
    conv_combine<<<dim3((B * 64 * HW) / 256), blk, 0, stream>>>(cpart, g_ls, xs, xs1, 64, ICS);
    conv3x3_big<<<dim3(4, 16, B * ICS), blk, 0, stream>>>(xc, gc_w, w_lc, b_lc, cpart, 32, 128, 128, ICS);
    conv_combine<<<dim3((B * 128 * HW) / 256), blk, 0, stream>>>(cpart, g_lc, xc, xc1, 128, ICS);
    // attention features
    conv3x3_big<<<dim3(4, 4, B * ICS), blk, 0, stream>>>(xs1, nullptr, w_c1, nullptr, cpart, 0, 64, 32, ICS);
    conv_combine<<<dim3((B * 32 * HW) / 256), blk, 0, stream>>>(cpart, g_c1, nullptr, fs, 32, ICS);
    conv3x3_big<<<dim3(4, 4, B * ICS), blk, 0, stream>>>(xc1, nullptr, w_c2, nullptr, cpart, 0, 128, 32, ICS);
    conv_combine<<<dim3((B * 32 * HW) / 256), blk, 0, stream>>>(cpart, g_c2, nullptr, fc, 32, ICS);
    // att = fs^T fc  (+ attT into d_out scratch)
    att_gemm<<<dim3(16, 256, B), blk, 0, stream>>>(fs, fc, att, attT, N);
    // stats: column (Mc/Sc) and row (Mr/Sr)
    colstats_part<<<dim3(64, 16, B), blk, 0, stream>>>(att, Mp, Sp, N, 16);
    colstats_comb<<<dim3(16, B), blk, 0, stream>>>(Mp, Sp, Mc, Sc, nullptr, N, 16);
    rowstats<<<dim3(N, B), blk, 0, stream>>>(att, Mr, Sr, N);
    // outc = xc1 @ rowsoftmax(att)^T  via MFMA
    to_bf16<<<dim3(1024), blk, 0, stream>>>(xc1, xc1bf, (long)B * 128 * N);
    sm_gemm_mfma<128><<<dim3(128, 2, B), blk, 0, stream>>>(xc1bf, att, Mr, pg0, pg1, N);
    sm_reduce2<128><<<dim3((B * 128 * N) / 256), blk, 0, stream>>>(pg0, pg1, Sr, outc_w, N);
    // outs = xs1 @ colsoftmax(att)  via MFMA on attT
    to_bf16<<<dim3(512), blk, 0, stream>>>(xs1, xs1bf, (long)B * 64 * N);
    sm_gemm_mfma<64><<<dim3(128, 2, B), blk, 0, stream>>>(xs1bf, attT, Mc, pg0, pg1, N);
    sm_reduce2<64><<<dim3((B * 64 * N) / 256), blk, 0, stream>>>(pg0, pg1, Sc, outs_w, N);
    // att2 = att + attT (streaming, in place) with fused column partial stats
    att2_stream<<<dim3(64, 32, B), blk, 0, stream>>>(att, attT, Mp2, Sp2, N);
    colstats_comb<<<dim3(16, B), blk, 0, stream>>>(Mp2, Sp2, M2, S2, C2L, N, 32);
    // fused att3 + 3x3 conv + BN + ReLU (overwrites attT region with final map)
    attmap_conv<<<dim3(8192, B), blk, 0, stream>>>(att, C2L, w_oa, g_oa, out_attmap, N);
    // output convs + residuals
    conv3x3_big<<<dim3(4, 8, B * ICS), blk, 0, stream>>>(outs_w, nullptr, w_o1, nullptr, cpart, 0, 64, 64, ICS);
    conv_combine<<<dim3((B * 64 * HW) / 256), blk, 0, stream>>>(cpart, g_o1, xs1, out_s, 64, ICS);
    conv3x3_big<<<dim3(4, 16, B * ICS), blk, 0, stream>>>(outc_w, nullptr, w_o2, nullptr, cpart, 0, 128, 128, ICS);
    conv_combine<<<dim3((B * 128 * HW) / 256), blk, 0, stream>>>(cpart, g_o2, xc1, out_c, 128, ICS);
}